// Round 1
// baseline (553.817 us; speedup 1.0000x reference)
//
#include <hip/hip_runtime.h>
#include <stdint.h>

typedef unsigned short u16;
typedef __bf16 bf16x8 __attribute__((ext_vector_type(8)));
typedef u16   u16x8  __attribute__((ext_vector_type(8)));
typedef float f32x4  __attribute__((ext_vector_type(4)));

#define GLOBAL_AS __attribute__((address_space(1)))
#define LDS_AS __attribute__((address_space(3)))

#define MDIM 8192
#define NDIM 4096
#define KDIM 4096
#define RDIM 16

// path-B (fallback) tile params
#define BM 128
#define BN 128
#define BK 64
#define EXTS 40

// ws layout (path A): [x_bf16 64MB][W_bf16 32MB][A_bf16 128KB][t fp32 512KB]
#define XBF_OFF 0
#define WBF_OFF (MDIM * KDIM * 2)
#define ABF_OFF (WBF_OFF + NDIM * KDIM * 2)
#define T_OFF   (ABF_OFF + RDIM * KDIM * 2)
#define WS_NEED ((size_t)T_OFF + MDIM * RDIM * 4)

#define XN8 (MDIM * KDIM / 8)
#define WN8 (NDIM * KDIM / 8)
#define AN8 (RDIM * KDIM / 8)

__device__ __forceinline__ u16 f2bf(float f) {
    union { float f; uint32_t u; } un;
    un.f = f;
    uint32_t u = un.u;
    u += 0x7FFFu + ((u >> 16) & 1u);   // round-to-nearest-even
    return (u16)(u >> 16);
}

__device__ __forceinline__ void cvt8(const float* __restrict__ p, u16* __restrict__ d) {
    f32x4 a = *(const f32x4*)p;
    f32x4 b = *(const f32x4*)(p + 4);
    u16x8 o;
    o[0] = f2bf(a[0]); o[1] = f2bf(a[1]); o[2] = f2bf(a[2]); o[3] = f2bf(a[3]);
    o[4] = f2bf(b[0]); o[5] = f2bf(b[1]); o[6] = f2bf(b[2]); o[7] = f2bf(b[3]);
    *(u16x8*)d = o;
}

// ---------------------------------------------------------------------------
// fused fp32->bf16 convert for x, W, A (one launch)
// ---------------------------------------------------------------------------
__global__ __launch_bounds__(256) void cvt_all_kernel(
        const float* __restrict__ x, const float* __restrict__ W,
        const float* __restrict__ A,
        u16* __restrict__ xbf, u16* __restrict__ Wbf, u16* __restrict__ Abf) {
    const int total = XN8 + WN8 + AN8;
    int i = blockIdx.x * blockDim.x + threadIdx.x;
    const int stride = gridDim.x * blockDim.x;
    for (; i < total; i += stride) {
        if (i < XN8) {
            cvt8(x + (size_t)i * 8, xbf + (size_t)i * 8);
        } else if (i < XN8 + WN8) {
            const int j = i - XN8;
            cvt8(W + (size_t)j * 8, Wbf + (size_t)j * 8);
        } else {
            const int j = i - XN8 - WN8;
            cvt8(A + (size_t)j * 8, Abf + (size_t)j * 8);
        }
    }
}

// ---------------------------------------------------------------------------
// Kernel 1: t[n][r] = sum_i x[n,i]*A[r,i], bf16 in / fp32 out (16x16x32)
// ---------------------------------------------------------------------------
__global__ __launch_bounds__(256) void lora_t_kernel(
        const u16* __restrict__ x, const u16* __restrict__ A,
        float* __restrict__ t) {
    const int wave = threadIdx.x >> 6;
    const int lane = threadIdx.x & 63;
    const int rl   = lane & 15;
    const int quad = lane >> 4;
    const int m0   = (blockIdx.x * 4 + wave) * 16;

    const u16* xp = x + (size_t)(m0 + rl) * KDIM + quad * 8;  // A-op: x[m][k]
    const u16* ap = A + (size_t)rl * KDIM + quad * 8;         // B-op: B[k][n]=A[n][k]

    f32x4 acc = {0.f, 0.f, 0.f, 0.f};
#pragma unroll 8
    for (int k = 0; k < KDIM; k += 32) {
        bf16x8 av = *(const bf16x8*)(xp + k);
        bf16x8 bv = *(const bf16x8*)(ap + k);
        acc = __builtin_amdgcn_mfma_f32_16x16x32_bf16(av, bv, acc, 0, 0, 0);
    }
    const int orow = m0 + quad * 4;   // C/D: col=lane&15, row=quad*4+v
#pragma unroll
    for (int v = 0; v < 4; ++v)
        t[(size_t)(orow + v) * RDIM + rl] = acc[v];
}

// Kernel 1 (path B): fp32 inputs, inline cvt
__global__ __launch_bounds__(256) void lora_t_inline_kernel(
        const float* __restrict__ x, const float* __restrict__ A,
        float* __restrict__ t) {
    const int wave = threadIdx.x >> 6;
    const int lane = threadIdx.x & 63;
    const int rl   = lane & 15;
    const int quad = lane >> 4;
    const int m0   = (blockIdx.x * 4 + wave) * 16;

    const float* xp = x + (size_t)(m0 + rl) * KDIM + quad * 8;
    const float* ap = A + (size_t)rl * KDIM + quad * 8;

    f32x4 acc = {0.f, 0.f, 0.f, 0.f};
    for (int k = 0; k < KDIM; k += 32) {
        f32x4 a0 = *(const f32x4*)(xp + k), a1 = *(const f32x4*)(xp + k + 4);
        f32x4 b0 = *(const f32x4*)(ap + k), b1 = *(const f32x4*)(ap + k + 4);
        u16x8 av, bv;
#pragma unroll
        for (int j = 0; j < 4; ++j) {
            av[j] = f2bf(a0[j]); av[j + 4] = f2bf(a1[j]);
            bv[j] = f2bf(b0[j]); bv[j + 4] = f2bf(b1[j]);
        }
        acc = __builtin_amdgcn_mfma_f32_16x16x32_bf16(
            (bf16x8)av, (bf16x8)bv, acc, 0, 0, 0);
    }
    const int orow = m0 + quad * 4;
#pragma unroll
    for (int v = 0; v < 4; ++v)
        t[(size_t)(orow + v) * RDIM + rl] = acc[v];
}

// ---------------------------------------------------------------------------
// Kernel 2 (path A): 256x256 tile, 8-phase schedule (T2+T3+T4+T5).
// 8 waves (2M x 4N), each wave owns a 128x64 C footprint split as 64x32
// pieces across the four 128x128 C-quadrants. Per K-tile (BK=64): 4 phases,
// one C-quadrant each; each phase reads only A-half Qm + B-half Qn, so
// half-tile prefetch into the released halves is race-free.
// Per phase: 12 ds_read_b128 || 1 half-tile stage (2x global_load_lds w=16)
// -> s_barrier -> lgkmcnt(0) -> setprio(1) -> 16x mfma 16x16x32 -> setprio(0)
// -> [vmcnt(4) once per K-tile] -> s_barrier.   vmcnt never 0 in main loop.
// LoRA ext (K=16 padded to 32) + bias in epilogue; fp32 store.
// ---------------------------------------------------------------------------
#define BK2   64
#define HTILE 8192          // u16 per half-tile (128 rows x 64 k)
#define ABUF  16384         // u16 per K-tile buffer (2 halves)
#define BOFFS 32768         // u16 offset of B region
#define NKT   (KDIM / BK2)  // 64

// stage one half-tile: LDS dest linear (wave-uniform base + lane*16),
// swizzle applied on the global gather side: LDS[row][c7] = G[row][c7^(row&7)]
#define STAGE(gsrc, half, kt, par, ab) do {                                   \
    const int _b = (par) * ABUF + (ab) * BOFFS + (half) * HTILE;              \
    _Pragma("unroll")                                                         \
    for (int _q = 0; _q < 2; ++_q) {                                          \
        const int _c   = _q * 512 + tid;                                      \
        const int _row = _c >> 3;                                             \
        const int _kc  = (_c & 7) ^ (_row & 7);                               \
        __builtin_amdgcn_global_load_lds(                                     \
            (const GLOBAL_AS uint32_t*)((gsrc) +                              \
                (size_t)((half) * 128 + _row) * KDIM + (kt) * BK2 + _kc * 8), \
            (LDS_AS uint32_t*)(smem + _b + _c * 8), 16, 0, 0);                \
    } } while (0)

#define NOSTAGE ((void)0)
#define VM4 asm volatile("s_waitcnt vmcnt(4)" ::: "memory")
#define VM0 asm volatile("s_waitcnt vmcnt(0)" ::: "memory")

#define PHASE(QM, QN, BC, S, WA) do {                                         \
    bf16x8 af[4][2], bfr[2][2];                                               \
    const u16* _ab = smem + (BC) * ABUF + (QM) * HTILE;                       \
    const u16* _bb = smem + BOFFS + (BC) * ABUF + (QN) * HTILE;               \
    _Pragma("unroll")                                                         \
    for (int i = 0; i < 4; ++i) {                                             \
        const int r_ = wm * 64 + i * 16 + rl;                                 \
        _Pragma("unroll")                                                     \
        for (int kk = 0; kk < 2; ++kk)                                        \
            af[i][kk] = *(const bf16x8*)(_ab + r_ * 64 +                      \
                                         (((kk * 4 + q4) ^ (r_ & 7)) * 8));   \
    }                                                                         \
    _Pragma("unroll")                                                         \
    for (int j = 0; j < 2; ++j) {                                             \
        const int r_ = wn * 32 + j * 16 + rl;                                 \
        _Pragma("unroll")                                                     \
        for (int kk = 0; kk < 2; ++kk)                                        \
            bfr[j][kk] = *(const bf16x8*)(_bb + r_ * 64 +                     \
                                          (((kk * 4 + q4) ^ (r_ & 7)) * 8));  \
    }                                                                         \
    S;                                                                        \
    __builtin_amdgcn_s_barrier();                                             \
    asm volatile("s_waitcnt lgkmcnt(0)" ::: "memory");                        \
    __builtin_amdgcn_s_setprio(1);                                            \
    _Pragma("unroll")                                                         \
    for (int i = 0; i < 4; ++i)                                               \
        _Pragma("unroll")                                                     \
        for (int j = 0; j < 2; ++j)                                           \
            _Pragma("unroll")                                                 \
            for (int kk = 0; kk < 2; ++kk)                                    \
                acc[QM][QN][i][j] = __builtin_amdgcn_mfma_f32_16x16x32_bf16(  \
                    af[i][kk], bfr[j][kk], acc[QM][QN][i][j], 0, 0, 0);       \
    __builtin_amdgcn_s_setprio(0);                                            \
    WA;                                                                       \
    __builtin_amdgcn_s_barrier();                                             \
} while (0)

__global__ __launch_bounds__(512, 2) void gemm8_lora_kernel(
        const u16* __restrict__ x, const u16* __restrict__ W,
        const float* __restrict__ bias, const float* __restrict__ Bl,
        const float* __restrict__ tmat, float* __restrict__ out) {
    __shared__ __align__(16) u16 smem[65536];   // 128 KiB

    const int tid  = threadIdx.x;
    const int lane = tid & 63;
    const int wave = tid >> 6;
    const int wm   = wave >> 2;       // 0..1
    const int wn   = wave & 3;        // 0..3
    const int rl   = lane & 15;
    const int q4   = lane >> 4;
    const int bm   = blockIdx.y * 256;
    const int bn   = blockIdx.x * 256;

    const u16* gA = x + (size_t)bm * KDIM;
    const u16* gB = W + (size_t)bn * KDIM;

    f32x4 acc[2][2][4][2];
#pragma unroll
    for (int a = 0; a < 2; ++a)
#pragma unroll
        for (int b = 0; b < 2; ++b)
#pragma unroll
            for (int i = 0; i < 4; ++i)
#pragma unroll
                for (int j = 0; j < 2; ++j)
                    acc[a][b][i][j] = (f32x4){0.f, 0.f, 0.f, 0.f};

    // prologue: t0 complete + A0/B0 of t1; keep 2 half-tiles in flight
    STAGE(gA, 0, 0, 0, 0); STAGE(gB, 0, 0, 0, 1);
    STAGE(gA, 1, 0, 0, 0); STAGE(gB, 1, 0, 0, 1);
    STAGE(gA, 0, 1, 1, 0); STAGE(gB, 0, 1, 1, 1);
    VM4;                               // t0 resident; A0(t1),B0(t1) in flight
    __builtin_amdgcn_s_barrier();

    // main loop: computes (t, t+1); stages A1/B1(t+1), A0/B0(t+2) during t's
    // phases and A1/B1(t+2), A0/B0(t+3) during t+1's phases.
    for (int t = 0; t < NKT - 2; t += 2) {
        PHASE(0, 0, 0, STAGE(gA, 1, t + 1, 1, 0), NOSTAGE);
        PHASE(0, 1, 0, STAGE(gB, 1, t + 1, 1, 1), NOSTAGE);
        PHASE(1, 0, 0, STAGE(gA, 0, t + 2, 0, 0), NOSTAGE);
        PHASE(1, 1, 0, STAGE(gB, 0, t + 2, 0, 1), VM4);
        PHASE(0, 0, 1, STAGE(gA, 1, t + 2, 0, 0), NOSTAGE);
        PHASE(0, 1, 1, STAGE(gB, 1, t + 2, 0, 1), NOSTAGE);
        PHASE(1, 0, 1, STAGE(gA, 0, t + 3, 1, 0), NOSTAGE);
        PHASE(1, 1, 1, STAGE(gB, 0, t + 3, 1, 1), VM4);
    }

    // drain epilogue: t = NKT-2 (buf0), t = NKT-1 (buf1)
    PHASE(0, 0, 0, STAGE(gA, 1, NKT - 1, 1, 0), NOSTAGE);
    PHASE(0, 1, 0, STAGE(gB, 1, NKT - 1, 1, 1), NOSTAGE);
    PHASE(1, 0, 0, NOSTAGE, NOSTAGE);
    PHASE(1, 1, 0, NOSTAGE, VM0);      // only place vmcnt drains to 0
    PHASE(0, 0, 1, NOSTAGE, NOSTAGE);
    PHASE(0, 1, 1, NOSTAGE, NOSTAGE);
    PHASE(1, 0, 1, NOSTAGE, NOSTAGE);
    PHASE(1, 1, 1, NOSTAGE, NOSTAGE);

    // ---- LoRA ext overlay: extA[256][32]=2t (bf16), extB[256][32]=Bl ----
    {
        u16x8 z = {0, 0, 0, 0, 0, 0, 0, 0};
        if (tid < 256) {
            const float* tp = tmat + (size_t)(bm + tid) * RDIM;
            u16* d = smem + tid * 32;
            f32x4 t0 = *(const f32x4*)tp,       t1 = *(const f32x4*)(tp + 4);
            f32x4 t2 = *(const f32x4*)(tp + 8), t3 = *(const f32x4*)(tp + 12);
            u16x8 o0, o1;
#pragma unroll
            for (int j = 0; j < 4; ++j) {
                o0[j] = f2bf(2.0f * t0[j]); o0[j + 4] = f2bf(2.0f * t1[j]);
                o1[j] = f2bf(2.0f * t2[j]); o1[j + 4] = f2bf(2.0f * t3[j]);
            }
            *(u16x8*)d = o0; *(u16x8*)(d + 8) = o1;
            *(u16x8*)(d + 16) = z; *(u16x8*)(d + 24) = z;
        } else {
            const int r = tid - 256;
            const float* bp = Bl + (size_t)(bn + r) * RDIM;
            u16* d = smem + BOFFS + r * 32;
            f32x4 b0 = *(const f32x4*)bp,       b1 = *(const f32x4*)(bp + 4);
            f32x4 b2 = *(const f32x4*)(bp + 8), b3 = *(const f32x4*)(bp + 12);
            u16x8 o0, o1;
#pragma unroll
            for (int j = 0; j < 4; ++j) {
                o0[j] = f2bf(b0[j]); o0[j + 4] = f2bf(b1[j]);
                o1[j] = f2bf(b2[j]); o1[j + 4] = f2bf(b3[j]);
            }
            *(u16x8*)d = o0; *(u16x8*)(d + 8) = o1;
            *(u16x8*)(d + 16) = z; *(u16x8*)(d + 24) = z;
        }
    }
    __syncthreads();

    // ext MFMA: one 16x16x32 per C-subtile (upper 16 k are zeros)
    {
        bf16x8 ae[2][4], be[2][2];
#pragma unroll
        for (int h = 0; h < 2; ++h)
#pragma unroll
            for (int i = 0; i < 4; ++i) {
                const int r_ = h * 128 + wm * 64 + i * 16 + rl;
                ae[h][i] = *(const bf16x8*)(smem + r_ * 32 + q4 * 8);
            }
#pragma unroll
        for (int h = 0; h < 2; ++h)
#pragma unroll
            for (int j = 0; j < 2; ++j) {
                const int r_ = h * 128 + wn * 32 + j * 16 + rl;
                be[h][j] = *(const bf16x8*)(smem + BOFFS + r_ * 32 + q4 * 8);
            }
#pragma unroll
        for (int a = 0; a < 2; ++a)
#pragma unroll
            for (int b = 0; b < 2; ++b)
#pragma unroll
                for (int i = 0; i < 4; ++i)
#pragma unroll
                    for (int j = 0; j < 2; ++j)
                        acc[a][b][i][j] = __builtin_amdgcn_mfma_f32_16x16x32_bf16(
                            ae[a][i], be[b][j], acc[a][b][i][j], 0, 0, 0);
    }

    // epilogue: + bias, fp32 store. C/D: col=lane&15, row=q4*4+v
    float bv[2][2];
#pragma unroll
    for (int h = 0; h < 2; ++h)
#pragma unroll
        for (int j = 0; j < 2; ++j)
            bv[h][j] = bias[bn + h * 128 + wn * 32 + j * 16 + rl];
#pragma unroll
    for (int a = 0; a < 2; ++a)
#pragma unroll
        for (int i = 0; i < 4; ++i) {
            const int row0 = bm + a * 128 + wm * 64 + i * 16 + q4 * 4;
#pragma unroll
            for (int b = 0; b < 2; ++b)
#pragma unroll
                for (int j = 0; j < 2; ++j) {
                    const int gcol = bn + b * 128 + wn * 32 + j * 16 + rl;
#pragma unroll
                    for (int v = 0; v < 4; ++v)
                        out[(size_t)(row0 + v) * NDIM + gcol] =
                            acc[a][b][i][j][v] + bv[b][j];
                }
        }
}

// ---------------------------------------------------------------------------
// Path B fallback (unchanged): fp32 x/W, inline cvt, 128x128 tile
// ---------------------------------------------------------------------------
__device__ __forceinline__ void stage_ext_b(
        int tid, int bm, int bn,
        const float* __restrict__ t, const float* __restrict__ bias,
        const float* __restrict__ Bl, u16* eA, u16* eB) {
    if (tid < 128) {
        const int r = tid;
        const float* tp = t + (size_t)(bm + r) * RDIM;
        u16* d = eA + r * EXTS;
#pragma unroll
        for (int j = 0; j < RDIM; ++j) d[j] = f2bf(2.0f * tp[j]);
        d[16] = 0x3F80;                                  // 1.0 bf16
#pragma unroll
        for (int j = 17; j < 32; ++j) d[j] = 0;
    } else {
        const int r = tid - 128;
        const float* bp = Bl + (size_t)(bn + r) * RDIM;
        u16* d = eB + r * EXTS;
#pragma unroll
        for (int j = 0; j < RDIM; ++j) d[j] = f2bf(bp[j]);
        d[16] = f2bf(bias[bn + r]);
#pragma unroll
        for (int j = 17; j < 32; ++j) d[j] = 0;
    }
}

__global__ __launch_bounds__(256) void gemm_lora_inline_kernel(
        const float* __restrict__ x, const float* __restrict__ W,
        const float* __restrict__ bias, const float* __restrict__ Bl,
        const float* __restrict__ t, float* __restrict__ out) {
    __shared__ __align__(16) u16 sA[BM * BK];
    __shared__ __align__(16) u16 sB[BN * BK];
    __shared__ __align__(16) u16 sAe[BM * EXTS];
    __shared__ __align__(16) u16 sBe[BN * EXTS];

    const int tid  = threadIdx.x;
    const int lane = tid & 63;
    const int wave = tid >> 6;
    const int wm   = wave >> 1;
    const int wn   = wave & 1;
    const int rl   = lane & 15;
    const int quad = lane >> 4;
    const int bm   = blockIdx.y * BM;
    const int bn   = blockIdx.x * BN;

    stage_ext_b(tid, bm, bn, t, bias, Bl, sAe, sBe);

    const float* gA = x + (size_t)bm * KDIM;
    const float* gB = W + (size_t)bn * KDIM;

    const int row0 = tid >> 3;
    const int kc0  = tid & 7;

    f32x4 acc[4][4];
#pragma unroll
    for (int i = 0; i < 4; ++i)
#pragma unroll
        for (int j = 0; j < 4; ++j)
            acc[i][j] = (f32x4){0.f, 0.f, 0.f, 0.f};

    for (int kt = 0; kt < KDIM; kt += BK) {
        u16x8 ra[4], rb[4];
#pragma unroll
        for (int q = 0; q < 4; ++q) {
            const int row = q * 32 + row0;
            const int kc  = kc0 ^ (row & 7);
            const size_t base = (size_t)row * KDIM + kt + kc * 8;
            f32x4 a0 = *(const f32x4*)(gA + base), a1 = *(const f32x4*)(gA + base + 4);
            f32x4 b0 = *(const f32x4*)(gB + base), b1 = *(const f32x4*)(gB + base + 4);
#pragma unroll
            for (int j = 0; j < 4; ++j) {
                ra[q][j] = f2bf(a0[j]); ra[q][j + 4] = f2bf(a1[j]);
                rb[q][j] = f2bf(b0[j]); rb[q][j + 4] = f2bf(b1[j]);
            }
        }
        __syncthreads();
#pragma unroll
        for (int q = 0; q < 4; ++q) {
            const int c = q * 256 + tid;
            *(u16x8*)(sA + c * 8) = ra[q];
            *(u16x8*)(sB + c * 8) = rb[q];
        }
        __syncthreads();

#pragma unroll
        for (int kk = 0; kk < 2; ++kk) {
            const int lc = kk * 4 + quad;
            bf16x8 af[4], bfv[4];
#pragma unroll
            for (int i = 0; i < 4; ++i) {
                const int rra = wm * 64 + i * 16 + rl;
                const int rrb = wn * 64 + i * 16 + rl;
                af[i]  = *(const bf16x8*)(sA + rra * BK + (lc ^ (rra & 7)) * 8);
                bfv[i] = *(const bf16x8*)(sB + rrb * BK + (lc ^ (rrb & 7)) * 8);
            }
#pragma unroll
            for (int i = 0; i < 4; ++i)
#pragma unroll
                for (int j = 0; j < 4; ++j)
                    acc[i][j] = __builtin_amdgcn_mfma_f32_16x16x32_bf16(
                        af[i], bfv[j], acc[i][j], 0, 0, 0);
        }
    }

    {
        const int ko = quad * 8;
        bf16x8 af[4], bfv[4];
#pragma unroll
        for (int i = 0; i < 4; ++i) {
            af[i]  = *(const bf16x8*)(sAe + (wm * 64 + i * 16 + rl) * EXTS + ko);
            bfv[i] = *(const bf16x8*)(sBe + (wn * 64 + i * 16 + rl) * EXTS + ko);
        }
#pragma unroll
        for (int i = 0; i < 4; ++i)
#pragma unroll
            for (int j = 0; j < 4; ++j)
                acc[i][j] = __builtin_amdgcn_mfma_f32_16x16x32_bf16(
                    af[i], bfv[j], acc[i][j], 0, 0, 0);
    }

#pragma unroll
    for (int i = 0; i < 4; ++i) {
        const int grow = bm + wm * 64 + i * 16 + quad * 4;
#pragma unroll
        for (int j = 0; j < 4; ++j) {
            const int gcol = bn + wn * 64 + j * 16 + rl;
#pragma unroll
            for (int v = 0; v < 4; ++v)
                out[(size_t)(grow + v) * NDIM + gcol] = acc[i][j][v];
        }
    }
}

// ---------------------------------------------------------------------------
extern "C" void kernel_launch(void* const* d_in, const int* in_sizes, int n_in,
                              void* d_out, int out_size, void* d_ws, size_t ws_size,
                              hipStream_t stream) {
    const float* x  = (const float*)d_in[0];  // (8192, 4096) fp32
    const float* W  = (const float*)d_in[1];  // (4096, 4096) fp32
    const float* b  = (const float*)d_in[2];  // (4096,)      fp32
    const float* A  = (const float*)d_in[3];  // (16, 4096)   fp32
    const float* Bl = (const float*)d_in[4];  // (4096, 16)   fp32
    float* out = (float*)d_out;               // (8192, 4096) fp32
    char* ws = (char*)d_ws;

    if (ws_size >= WS_NEED) {
        u16*   xbf = (u16*)(ws + XBF_OFF);
        u16*   Wbf = (u16*)(ws + WBF_OFF);
        u16*   Abf = (u16*)(ws + ABF_OFF);
        float* t   = (float*)(ws + T_OFF);

        dim3 grid8(NDIM / 256, MDIM / 256);   // (16, 32) = 512 blocks
        cvt_all_kernel<<<4096, 256, 0, stream>>>(x, W, A, xbf, Wbf, Abf);
        lora_t_kernel<<<128, 256, 0, stream>>>(xbf, Abf, t);
        gemm8_lora_kernel<<<grid8, 512, 0, stream>>>(xbf, Wbf, b, Bl, t, out);
    } else {
        float* t = (float*)ws;
        dim3 grid(NDIM / BN, MDIM / BM);      // (32, 64)
        lora_t_inline_kernel<<<128, 256, 0, stream>>>(x, A, t);
        gemm_lora_inline_kernel<<<grid, 256, 0, stream>>>(x, W, b, Bl, t, out);
    }
}

// Round 2
// 531.551 us; speedup vs baseline: 1.0419x; 1.0419x over previous
//
#include <hip/hip_runtime.h>
#include <stdint.h>

typedef unsigned short u16;
typedef __bf16 bf16x8 __attribute__((ext_vector_type(8)));
typedef u16   u16x8  __attribute__((ext_vector_type(8)));
typedef float f32x4  __attribute__((ext_vector_type(4)));

#define GLOBAL_AS __attribute__((address_space(1)))
#define LDS_AS __attribute__((address_space(3)))

#define MDIM 8192
#define NDIM 4096
#define KDIM 4096
#define RDIM 16

// path-B (fallback) tile params
#define BM 128
#define BN 128
#define BK 64
#define EXTS 40

// ws layout (path A): [x_bf16 64MB][W_bf16 32MB][A_bf16 128KB][t fp32 512KB]
#define XBF_OFF 0
#define WBF_OFF (MDIM * KDIM * 2)
#define ABF_OFF (WBF_OFF + NDIM * KDIM * 2)
#define T_OFF   (ABF_OFF + RDIM * KDIM * 2)
#define WS_NEED ((size_t)T_OFF + MDIM * RDIM * 4)

#define XN8 (MDIM * KDIM / 8)
#define WN8 (NDIM * KDIM / 8)
#define AN8 (RDIM * KDIM / 8)

__device__ __forceinline__ u16 f2bf(float f) {
    union { float f; uint32_t u; } un;
    un.f = f;
    uint32_t u = un.u;
    u += 0x7FFFu + ((u >> 16) & 1u);   // round-to-nearest-even
    return (u16)(u >> 16);
}

__device__ __forceinline__ void cvt8(const float* __restrict__ p, u16* __restrict__ d) {
    f32x4 a = *(const f32x4*)p;
    f32x4 b = *(const f32x4*)(p + 4);
    u16x8 o;
    o[0] = f2bf(a[0]); o[1] = f2bf(a[1]); o[2] = f2bf(a[2]); o[3] = f2bf(a[3]);
    o[4] = f2bf(b[0]); o[5] = f2bf(b[1]); o[6] = f2bf(b[2]); o[7] = f2bf(b[3]);
    *(u16x8*)d = o;
}

// ---------------------------------------------------------------------------
// fused fp32->bf16 convert for x, W, A (one launch)
// ---------------------------------------------------------------------------
__global__ __launch_bounds__(256) void cvt_all_kernel(
        const float* __restrict__ x, const float* __restrict__ W,
        const float* __restrict__ A,
        u16* __restrict__ xbf, u16* __restrict__ Wbf, u16* __restrict__ Abf) {
    const int total = XN8 + WN8 + AN8;
    int i = blockIdx.x * blockDim.x + threadIdx.x;
    const int stride = gridDim.x * blockDim.x;
    for (; i < total; i += stride) {
        if (i < XN8) {
            cvt8(x + (size_t)i * 8, xbf + (size_t)i * 8);
        } else if (i < XN8 + WN8) {
            const int j = i - XN8;
            cvt8(W + (size_t)j * 8, Wbf + (size_t)j * 8);
        } else {
            const int j = i - XN8 - WN8;
            cvt8(A + (size_t)j * 8, Abf + (size_t)j * 8);
        }
    }
}

// ---------------------------------------------------------------------------
// Kernel 1: t[n][r] = sum_i x[n,i]*A[r,i], bf16 in / fp32 out (16x16x32)
// ---------------------------------------------------------------------------
__global__ __launch_bounds__(256) void lora_t_kernel(
        const u16* __restrict__ x, const u16* __restrict__ A,
        float* __restrict__ t) {
    const int wave = threadIdx.x >> 6;
    const int lane = threadIdx.x & 63;
    const int rl   = lane & 15;
    const int quad = lane >> 4;
    const int m0   = (blockIdx.x * 4 + wave) * 16;

    const u16* xp = x + (size_t)(m0 + rl) * KDIM + quad * 8;  // A-op: x[m][k]
    const u16* ap = A + (size_t)rl * KDIM + quad * 8;         // B-op: B[k][n]=A[n][k]

    f32x4 acc = {0.f, 0.f, 0.f, 0.f};
#pragma unroll 8
    for (int k = 0; k < KDIM; k += 32) {
        bf16x8 av = *(const bf16x8*)(xp + k);
        bf16x8 bv = *(const bf16x8*)(ap + k);
        acc = __builtin_amdgcn_mfma_f32_16x16x32_bf16(av, bv, acc, 0, 0, 0);
    }
    const int orow = m0 + quad * 4;   // C/D: col=lane&15, row=quad*4+v
#pragma unroll
    for (int v = 0; v < 4; ++v)
        t[(size_t)(orow + v) * RDIM + rl] = acc[v];
}

// Kernel 1 (path B): fp32 inputs, inline cvt
__global__ __launch_bounds__(256) void lora_t_inline_kernel(
        const float* __restrict__ x, const float* __restrict__ A,
        float* __restrict__ t) {
    const int wave = threadIdx.x >> 6;
    const int lane = threadIdx.x & 63;
    const int rl   = lane & 15;
    const int quad = lane >> 4;
    const int m0   = (blockIdx.x * 4 + wave) * 16;

    const float* xp = x + (size_t)(m0 + rl) * KDIM + quad * 8;
    const float* ap = A + (size_t)rl * KDIM + quad * 8;

    f32x4 acc = {0.f, 0.f, 0.f, 0.f};
    for (int k = 0; k < KDIM; k += 32) {
        f32x4 a0 = *(const f32x4*)(xp + k), a1 = *(const f32x4*)(xp + k + 4);
        f32x4 b0 = *(const f32x4*)(ap + k), b1 = *(const f32x4*)(ap + k + 4);
        u16x8 av, bv;
#pragma unroll
        for (int j = 0; j < 4; ++j) {
            av[j] = f2bf(a0[j]); av[j + 4] = f2bf(a1[j]);
            bv[j] = f2bf(b0[j]); bv[j + 4] = f2bf(b1[j]);
        }
        acc = __builtin_amdgcn_mfma_f32_16x16x32_bf16(
            (bf16x8)av, (bf16x8)bv, acc, 0, 0, 0);
    }
    const int orow = m0 + quad * 4;
#pragma unroll
    for (int v = 0; v < 4; ++v)
        t[(size_t)(orow + v) * RDIM + rl] = acc[v];
}

// ---------------------------------------------------------------------------
// Kernel 2 (path A): 256x256 tile, 8-phase schedule with FRAGMENT REG REUSE.
// 8 waves (2M x 4N). Per K-tile (BK=64): 4 phases = 4 C-quadrants.
//   P1: ds_read A0(8)+B0(4) -> Q00    P2: ds_read B1(4) -> Q01 (A0 reused)
//   P3: ds_read A1(8) -> Q10 (B0 reused)   P4: no reads -> Q11 (A1,B1 reused)
// 24 ds_read_b128 per K-tile per wave (the per-wave operand floor) vs 48
// in the naive re-read schedule; the kernel is LDS-read-BW-bound so this
// directly scales the K-tile critical path.
// vmcnt: VM4 at P4/P8 only (2 half-tiles stay in flight), VM0 only in drain.
// LoRA ext (K=16 padded to 32) + bias in epilogue; fp32 store.
// ---------------------------------------------------------------------------
#define BK2   64
#define HTILE 8192          // u16 per half-tile (128 rows x 64 k)
#define ABUF  16384         // u16 per K-tile buffer (2 halves)
#define BOFFS 32768         // u16 offset of B region
#define NKT   (KDIM / BK2)  // 64

// stage one half-tile: LDS dest linear (wave-uniform base + lane*16),
// swizzle applied on the global gather side: LDS[row][c7] = G[row][c7^(row&7)]
#define STAGE(gsrc, half, kt, par, ab) do {                                   \
    const int _b = (par) * ABUF + (ab) * BOFFS + (half) * HTILE;              \
    _Pragma("unroll")                                                         \
    for (int _q = 0; _q < 2; ++_q) {                                          \
        const int _c   = _q * 512 + tid;                                      \
        const int _row = _c >> 3;                                             \
        const int _kc  = (_c & 7) ^ (_row & 7);                               \
        __builtin_amdgcn_global_load_lds(                                     \
            (const GLOBAL_AS uint32_t*)((gsrc) +                              \
                (size_t)((half) * 128 + _row) * KDIM + (kt) * BK2 + _kc * 8), \
            (LDS_AS uint32_t*)(smem + _b + _c * 8), 16, 0, 0);                \
    } } while (0)

#define NOSTAGE ((void)0)
#define VM4 asm volatile("s_waitcnt vmcnt(4)" ::: "memory")
#define VM0 asm volatile("s_waitcnt vmcnt(0)" ::: "memory")
#define LGKM0 asm volatile("s_waitcnt lgkmcnt(0)" ::: "memory")

// ds_read A fragments (4 row-groups x 2 k-chunks) from half-tile at abase
#define READ_A(dst, abase) do {                                               \
    _Pragma("unroll")                                                         \
    for (int i = 0; i < 4; ++i) {                                             \
        const int r_ = wm * 64 + i * 16 + rl;                                 \
        _Pragma("unroll")                                                     \
        for (int kk = 0; kk < 2; ++kk)                                        \
            dst[i][kk] = *(const bf16x8*)((abase) + r_ * 64 +                 \
                                          (((kk * 4 + q4) ^ (r_ & 7)) * 8));  \
    } } while (0)

// ds_read B fragments (2 row-groups x 2 k-chunks)
#define READ_B(dst, bbase) do {                                               \
    _Pragma("unroll")                                                         \
    for (int j = 0; j < 2; ++j) {                                             \
        const int r_ = wn * 32 + j * 16 + rl;                                 \
        _Pragma("unroll")                                                     \
        for (int kk = 0; kk < 2; ++kk)                                        \
            dst[j][kk] = *(const bf16x8*)((bbase) + r_ * 64 +                 \
                                          (((kk * 4 + q4) ^ (r_ & 7)) * 8));  \
    } } while (0)

// 16 MFMA: one C-quadrant, full K=64
#define MFMA_Q(QM, QN, a_, b_) do {                                           \
    __builtin_amdgcn_s_setprio(1);                                            \
    _Pragma("unroll")                                                         \
    for (int i = 0; i < 4; ++i)                                               \
        _Pragma("unroll")                                                     \
        for (int j = 0; j < 2; ++j)                                           \
            _Pragma("unroll")                                                 \
            for (int kk = 0; kk < 2; ++kk)                                    \
                acc[QM][QN][i][j] = __builtin_amdgcn_mfma_f32_16x16x32_bf16(  \
                    a_[i][kk], b_[j][kk], acc[QM][QN][i][j], 0, 0, 0);        \
    __builtin_amdgcn_s_setprio(0);                                            \
} while (0)

#define BARRIER __builtin_amdgcn_s_barrier()

// one K-tile = 4 phases; S1..S4 stage slots, W4 = wait before final barrier
#define KTILE(BC, S1, S2, S3, S4, W4) do {                                    \
    bf16x8 a_[4][2], b0_[2][2], b1_[2][2];                                    \
    const u16* _ab = smem + (BC) * ABUF;                                      \
    const u16* _bb = smem + BOFFS + (BC) * ABUF;                              \
    /* P1: A0 + B0 -> Q00 */                                                  \
    READ_A(a_, _ab);                                                          \
    READ_B(b0_, _bb);                                                         \
    S1; BARRIER; LGKM0; MFMA_Q(0, 0, a_, b0_); BARRIER;                       \
    /* P2: B1 -> Q01 (A0 reused) */                                           \
    READ_B(b1_, _bb + HTILE);                                                 \
    S2; BARRIER; LGKM0; MFMA_Q(0, 1, a_, b1_); BARRIER;                       \
    /* P3: A1 -> Q10 (B0 reused) */                                           \
    READ_A(a_, _ab + HTILE);                                                  \
    S3; BARRIER; LGKM0; MFMA_Q(1, 0, a_, b0_); BARRIER;                       \
    /* P4: no reads -> Q11 (A1,B1 reused) */                                  \
    S4; BARRIER; MFMA_Q(1, 1, a_, b1_); W4; BARRIER;                          \
} while (0)

__global__ __launch_bounds__(512, 2) void gemm8_lora_kernel(
        const u16* __restrict__ x, const u16* __restrict__ W,
        const float* __restrict__ bias, const float* __restrict__ Bl,
        const float* __restrict__ tmat, float* __restrict__ out) {
    __shared__ __align__(16) u16 smem[65536];   // 128 KiB

    const int tid  = threadIdx.x;
    const int lane = tid & 63;
    const int wave = tid >> 6;
    const int wm   = wave >> 2;       // 0..1
    const int wn   = wave & 3;        // 0..3
    const int rl   = lane & 15;
    const int q4   = lane >> 4;
    const int bm   = blockIdx.y * 256;
    const int bn   = blockIdx.x * 256;

    const u16* gA = x + (size_t)bm * KDIM;
    const u16* gB = W + (size_t)bn * KDIM;

    f32x4 acc[2][2][4][2];
#pragma unroll
    for (int a = 0; a < 2; ++a)
#pragma unroll
        for (int b = 0; b < 2; ++b)
#pragma unroll
            for (int i = 0; i < 4; ++i)
#pragma unroll
                for (int j = 0; j < 2; ++j)
                    acc[a][b][i][j] = (f32x4){0.f, 0.f, 0.f, 0.f};

    // prologue: t0 complete + A0/B0 of t1; keep 2 half-tiles in flight
    STAGE(gA, 0, 0, 0, 0); STAGE(gB, 0, 0, 0, 1);
    STAGE(gA, 1, 0, 0, 0); STAGE(gB, 1, 0, 0, 1);
    STAGE(gA, 0, 1, 1, 0); STAGE(gB, 0, 1, 1, 1);
    VM4;                               // t0 resident; A0(t1),B0(t1) in flight
    BARRIER;

    // main loop: tiles (t, t+1); stage A1/B1(t+1), A0/B0(t+2) during tile t
    // and A1/B1(t+2), A0/B0(t+3) during tile t+1. VM4 once per K-tile.
    for (int t = 0; t < NKT - 2; t += 2) {
        KTILE(0, STAGE(gA, 1, t + 1, 1, 0), STAGE(gB, 1, t + 1, 1, 1),
                 STAGE(gA, 0, t + 2, 0, 0), STAGE(gB, 0, t + 2, 0, 1), VM4);
        KTILE(1, STAGE(gA, 1, t + 2, 0, 0), STAGE(gB, 1, t + 2, 0, 1),
                 STAGE(gA, 0, t + 3, 1, 0), STAGE(gB, 0, t + 3, 1, 1), VM4);
    }

    // drain: tile NKT-2 (buf0) stages the rest of tile NKT-1; VM0 once.
    KTILE(0, STAGE(gA, 1, NKT - 1, 1, 0), STAGE(gB, 1, NKT - 1, 1, 1),
             NOSTAGE, NOSTAGE, VM0);
    KTILE(1, NOSTAGE, NOSTAGE, NOSTAGE, NOSTAGE, NOSTAGE);

    // ---- LoRA ext overlay: extA[256][32]=2t (bf16), extB[256][32]=Bl ----
    {
        u16x8 z = {0, 0, 0, 0, 0, 0, 0, 0};
        if (tid < 256) {
            const float* tp = tmat + (size_t)(bm + tid) * RDIM;
            u16* d = smem + tid * 32;
            f32x4 t0 = *(const f32x4*)tp,       t1 = *(const f32x4*)(tp + 4);
            f32x4 t2 = *(const f32x4*)(tp + 8), t3 = *(const f32x4*)(tp + 12);
            u16x8 o0, o1;
#pragma unroll
            for (int j = 0; j < 4; ++j) {
                o0[j] = f2bf(2.0f * t0[j]); o0[j + 4] = f2bf(2.0f * t1[j]);
                o1[j] = f2bf(2.0f * t2[j]); o1[j + 4] = f2bf(2.0f * t3[j]);
            }
            *(u16x8*)d = o0; *(u16x8*)(d + 8) = o1;
            *(u16x8*)(d + 16) = z; *(u16x8*)(d + 24) = z;
        } else {
            const int r = tid - 256;
            const float* bp = Bl + (size_t)(bn + r) * RDIM;
            u16* d = smem + BOFFS + r * 32;
            f32x4 b0 = *(const f32x4*)bp,       b1 = *(const f32x4*)(bp + 4);
            f32x4 b2 = *(const f32x4*)(bp + 8), b3 = *(const f32x4*)(bp + 12);
            u16x8 o0, o1;
#pragma unroll
            for (int j = 0; j < 4; ++j) {
                o0[j] = f2bf(b0[j]); o0[j + 4] = f2bf(b1[j]);
                o1[j] = f2bf(b2[j]); o1[j + 4] = f2bf(b3[j]);
            }
            *(u16x8*)d = o0; *(u16x8*)(d + 8) = o1;
            *(u16x8*)(d + 16) = z; *(u16x8*)(d + 24) = z;
        }
    }
    __syncthreads();

    // ext MFMA: one 16x16x32 per C-subtile (upper 16 k are zeros)
    {
        bf16x8 ae[2][4], be[2][2];
#pragma unroll
        for (int h = 0; h < 2; ++h)
#pragma unroll
            for (int i = 0; i < 4; ++i) {
                const int r_ = h * 128 + wm * 64 + i * 16 + rl;
                ae[h][i] = *(const bf16x8*)(smem + r_ * 32 + q4 * 8);
            }
#pragma unroll
        for (int h = 0; h < 2; ++h)
#pragma unroll
            for (int j = 0; j < 2; ++j) {
                const int r_ = h * 128 + wn * 32 + j * 16 + rl;
                be[h][j] = *(const bf16x8*)(smem + BOFFS + r_ * 32 + q4 * 8);
            }
#pragma unroll
        for (int a = 0; a < 2; ++a)
#pragma unroll
            for (int b = 0; b < 2; ++b)
#pragma unroll
                for (int i = 0; i < 4; ++i)
#pragma unroll
                    for (int j = 0; j < 2; ++j)
                        acc[a][b][i][j] = __builtin_amdgcn_mfma_f32_16x16x32_bf16(
                            ae[a][i], be[b][j], acc[a][b][i][j], 0, 0, 0);
    }

    // epilogue: + bias, fp32 store. C/D: col=lane&15, row=q4*4+v
    float bv[2][2];
#pragma unroll
    for (int h = 0; h < 2; ++h)
#pragma unroll
        for (int j = 0; j < 2; ++j)
            bv[h][j] = bias[bn + h * 128 + wn * 32 + j * 16 + rl];
#pragma unroll
    for (int a = 0; a < 2; ++a)
#pragma unroll
        for (int i = 0; i < 4; ++i) {
            const int row0 = bm + a * 128 + wm * 64 + i * 16 + q4 * 4;
#pragma unroll
            for (int b = 0; b < 2; ++b)
#pragma unroll
                for (int j = 0; j < 2; ++j) {
                    const int gcol = bn + b * 128 + wn * 32 + j * 16 + rl;
#pragma unroll
                    for (int v = 0; v < 4; ++v)
                        out[(size_t)(row0 + v) * NDIM + gcol] =
                            acc[a][b][i][j][v] + bv[b][j];
                }
        }
}

// ---------------------------------------------------------------------------
// Path B fallback (unchanged): fp32 x/W, inline cvt, 128x128 tile
// ---------------------------------------------------------------------------
__device__ __forceinline__ void stage_ext_b(
        int tid, int bm, int bn,
        const float* __restrict__ t, const float* __restrict__ bias,
        const float* __restrict__ Bl, u16* eA, u16* eB) {
    if (tid < 128) {
        const int r = tid;
        const float* tp = t + (size_t)(bm + r) * RDIM;
        u16* d = eA + r * EXTS;
#pragma unroll
        for (int j = 0; j < RDIM; ++j) d[j] = f2bf(2.0f * tp[j]);
        d[16] = 0x3F80;                                  // 1.0 bf16
#pragma unroll
        for (int j = 17; j < 32; ++j) d[j] = 0;
    } else {
        const int r = tid - 128;
        const float* bp = Bl + (size_t)(bn + r) * RDIM;
        u16* d = eB + r * EXTS;
#pragma unroll
        for (int j = 0; j < RDIM; ++j) d[j] = f2bf(bp[j]);
        d[16] = f2bf(bias[bn + r]);
#pragma unroll
        for (int j = 17; j < 32; ++j) d[j] = 0;
    }
}

__global__ __launch_bounds__(256) void gemm_lora_inline_kernel(
        const float* __restrict__ x, const float* __restrict__ W,
        const float* __restrict__ bias, const float* __restrict__ Bl,
        const float* __restrict__ t, float* __restrict__ out) {
    __shared__ __align__(16) u16 sA[BM * BK];
    __shared__ __align__(16) u16 sB[BN * BK];
    __shared__ __align__(16) u16 sAe[BM * EXTS];
    __shared__ __align__(16) u16 sBe[BN * EXTS];

    const int tid  = threadIdx.x;
    const int lane = tid & 63;
    const int wave = tid >> 6;
    const int wm   = wave >> 1;
    const int wn   = wave & 1;
    const int rl   = lane & 15;
    const int quad = lane >> 4;
    const int bm   = blockIdx.y * BM;
    const int bn   = blockIdx.x * BN;

    stage_ext_b(tid, bm, bn, t, bias, Bl, sAe, sBe);

    const float* gA = x + (size_t)bm * KDIM;
    const float* gB = W + (size_t)bn * KDIM;

    const int row0 = tid >> 3;
    const int kc0  = tid & 7;

    f32x4 acc[4][4];
#pragma unroll
    for (int i = 0; i < 4; ++i)
#pragma unroll
        for (int j = 0; j < 4; ++j)
            acc[i][j] = (f32x4){0.f, 0.f, 0.f, 0.f};

    for (int kt = 0; kt < KDIM; kt += BK) {
        u16x8 ra[4], rb[4];
#pragma unroll
        for (int q = 0; q < 4; ++q) {
            const int row = q * 32 + row0;
            const int kc  = kc0 ^ (row & 7);
            const size_t base = (size_t)row * KDIM + kt + kc * 8;
            f32x4 a0 = *(const f32x4*)(gA + base), a1 = *(const f32x4*)(gA + base + 4);
            f32x4 b0 = *(const f32x4*)(gB + base), b1 = *(const f32x4*)(gB + base + 4);
#pragma unroll
            for (int j = 0; j < 4; ++j) {
                ra[q][j] = f2bf(a0[j]); ra[q][j + 4] = f2bf(a1[j]);
                rb[q][j] = f2bf(b0[j]); rb[q][j + 4] = f2bf(b1[j]);
            }
        }
        __syncthreads();
#pragma unroll
        for (int q = 0; q < 4; ++q) {
            const int c = q * 256 + tid;
            *(u16x8*)(sA + c * 8) = ra[q];
            *(u16x8*)(sB + c * 8) = rb[q];
        }
        __syncthreads();

#pragma unroll
        for (int kk = 0; kk < 2; ++kk) {
            const int lc = kk * 4 + quad;
            bf16x8 af[4], bfv[4];
#pragma unroll
            for (int i = 0; i < 4; ++i) {
                const int rra = wm * 64 + i * 16 + rl;
                const int rrb = wn * 64 + i * 16 + rl;
                af[i]  = *(const bf16x8*)(sA + rra * BK + (lc ^ (rra & 7)) * 8);
                bfv[i] = *(const bf16x8*)(sB + rrb * BK + (lc ^ (rrb & 7)) * 8);
            }
#pragma unroll
            for (int i = 0; i < 4; ++i)
#pragma unroll
                for (int j = 0; j < 4; ++j)
                    acc[i][j] = __builtin_amdgcn_mfma_f32_16x16x32_bf16(
                        af[i], bfv[j], acc[i][j], 0, 0, 0);
        }
    }

    {
        const int ko = quad * 8;
        bf16x8 af[4], bfv[4];
#pragma unroll
        for (int i = 0; i < 4; ++i) {
            af[i]  = *(const bf16x8*)(sAe + (wm * 64 + i * 16 + rl) * EXTS + ko);
            bfv[i] = *(const bf16x8*)(sBe + (wn * 64 + i * 16 + rl) * EXTS + ko);
        }
#pragma unroll
        for (int i = 0; i < 4; ++i)
#pragma unroll
            for (int j = 0; j < 4; ++j)
                acc[i][j] = __builtin_amdgcn_mfma_f32_16x16x32_bf16(
                    af[i], bfv[j], acc[i][j], 0, 0, 0);
    }

#pragma unroll
    for (int i = 0; i < 4; ++i) {
        const int grow = bm + wm * 64 + i * 16 + quad * 4;
#pragma unroll
        for (int j = 0; j < 4; ++j) {
            const int gcol = bn + wn * 64 + j * 16 + rl;
#pragma unroll
            for (int v = 0; v < 4; ++v)
                out[(size_t)(grow + v) * NDIM + gcol] = acc[i][j][v];
        }
    }
}

// ---------------------------------------------------------------------------
extern "C" void kernel_launch(void* const* d_in, const int* in_sizes, int n_in,
                              void* d_out, int out_size, void* d_ws, size_t ws_size,
                              hipStream_t stream) {
    const float* x  = (const float*)d_in[0];  // (8192, 4096) fp32
    const float* W  = (const float*)d_in[1];  // (4096, 4096) fp32
    const float* b  = (const float*)d_in[2];  // (4096,)      fp32
    const float* A  = (const float*)d_in[3];  // (16, 4096)   fp32
    const float* Bl = (const float*)d_in[4];  // (4096, 16)   fp32
    float* out = (float*)d_out;               // (8192, 4096) fp32
    char* ws = (char*)d_ws;

    if (ws_size >= WS_NEED) {
        u16*   xbf = (u16*)(ws + XBF_OFF);
        u16*   Wbf = (u16*)(ws + WBF_OFF);
        u16*   Abf = (u16*)(ws + ABF_OFF);
        float* t   = (float*)(ws + T_OFF);

        dim3 grid8(NDIM / 256, MDIM / 256);   // (16, 32) = 512 blocks
        cvt_all_kernel<<<4096, 256, 0, stream>>>(x, W, A, xbf, Wbf, Abf);
        lora_t_kernel<<<128, 256, 0, stream>>>(xbf, Abf, t);
        gemm8_lora_kernel<<<grid8, 512, 0, stream>>>(xbf, Wbf, b, Bl, t, out);
    } else {
        float* t = (float*)ws;
        dim3 grid(NDIM / BN, MDIM / BM);      // (32, 64)
        lora_t_inline_kernel<<<128, 256, 0, stream>>>(x, A, t);
        gemm_lora_inline_kernel<<<grid, 256, 0, stream>>>(x, W, b, Bl, t, out);
    }
}